// Round 6
// baseline (176.179 us; speedup 1.0000x reference)
//
#include <hip/hip_runtime.h>
#include <math.h>

#define B_ 4
#define D_ 32
#define H_ 192
#define W_ 192
#define HW_ (H_ * W_)

#define NT 5            // Taylor terms p = 1..5

#define TW 48           // 12 real col-groups; stage-2 runs 16 groups (4 garbage)
#define TH 12
#define NTHR 256
#define ZCHUNK 8
#define NP (ZCHUNK + 8) // 16 staged planes; NP+1 = 17 pipelined iterations

#define XT_H 26         // TH + 14
#define XT_COLS 62      // TW + 14 staged cols
#define XT_W 64         // row stride in words: addr = 4*lane + 64*dh (dense)
#define XT_CELLS (XT_H * XT_COLS)   // 1612
#define NSEC 7
#define XT_SZ (XT_H * XT_W)         // 1664

// Stage-1 output R': per term, 12 rows x 16 quads (64 words)
#define R2_PL (TH * XT_W)     // 768 words per term-plane
#define RBUF (NT * R2_PL)     // 3840

// xt SINGLE-buffered (reads->barrier2->writes); R' double-buffered.
#define SMEM_WORDS (XT_SZ + 2 * RBUF + 16)   // 9360 words = 37.4 KB -> 4 blocks/CU

#define NTAPS (B_ * 9 * 15 * 15)

__device__ inline float4 f4fma(float c, float4 a, float4 d) {
    d.x = fmaf(c, a.x, d.x); d.y = fmaf(c, a.y, d.y);
    d.z = fmaf(c, a.z, d.z); d.w = fmaf(c, a.w, d.w);
    return d;
}
__device__ inline float4 f4add(float4 a, float4 b) {
    a.x += b.x; a.y += b.y; a.z += b.z; a.w += b.w; return a;
}
__device__ inline float rfl(float x) {
    return __int_as_float(__builtin_amdgcn_readfirstlane(__float_as_int(x)));
}
// lane l <- lane l+N within each 16-lane DPP row; out-of-row -> 0.
template<int N>
__device__ inline float dpp_shl(float v) {
    return __int_as_float(__builtin_amdgcn_update_dpp(
        0, __float_as_int(v), 0x100 | N, 0xF, 0xF, true));
}

// h-first separable-Taylor blur (R5 structure) + occupancy lever:
//   ZCHUNK=8 -> 1024 blocks; xt single-buffered (37.4 KB LDS) -> 4 blocks/CU
//   = 16 waves/CU (2x R5) to hide LDS latency and barrier convoys.
// Iteration: barrier1 -> [prefetch pv | s1: xt reads->fold->R'[p&1] |
//   s2: R'[(p-1)&1] + DPP window -> acc/store] -> barrier2 -> xt write (pv).
__global__ __launch_bounds__(NTHR)
void conv_kernel(const float* __restrict__ x,
                 const float* __restrict__ bet_xy,
                 const float* __restrict__ bet_z,
                 const float* __restrict__ alpha,
                 float* __restrict__ out) {
    __shared__ __align__(16) float smem[SMEM_WORDS];
    float* xtb = smem;                 // [XT_SZ] (single buffer)
    float* Rb  = smem + XT_SZ;         // [2][NT][R2_PL]
    float* red = smem;                 // alias: pre-loop only
    float* ct  = smem + 512;           // alias: pre-loop only, [NT][16]

    const int t  = threadIdx.x;
    const int w0 = blockIdx.x * TW;
    const int h0 = blockIdx.y * TH;
    const int bz = blockIdx.z;
    const int b  = bz & 3;
    const int z0 = (bz >> 2) * ZCHUNK;
    const float INV = 0.3989422804014327f;

    // ---- exact global sum S (deterministic, identical in every block) ----
    float local = 0.f;
#pragma unroll
    for (int s = 0; s < 32; ++s) {
        int idx = t + s * NTHR;
        if (idx < NTAPS) {
            int bb = idx / 2025;
            int r  = idx % 2025;
            int dz = r / 225;
            int r2 = r % 225;
            int dh = r2 / 15;
            int dw = r2 % 15;
            float bxy = bet_xy[bb], bzv = bet_z[bb], al = alpha[bb];
            float zd = (float)(dz - 4), hd = (float)(dh - 7), wd = (float)(dw - 7);
            float az = expf(-zd * zd / (2.f * bzv * bzv)) * (INV / bzv);
            float gh = expf(-hd * hd / (2.f * bxy * bxy)) * (INV / bxy);
            float gw = expf(-wd * wd / (2.f * bxy * bxy)) * (INV / bxy);
            local += 1.f - expf(-al * az * gh * gw);
        }
    }
    red[t] = local;
    __syncthreads();
    for (int s = 128; s > 0; s >>= 1) {
        if (t < s) red[t] += red[t + s];
        __syncthreads();
    }
    const float S = red[0];
    __syncthreads();

    // ---- own batch's coefficient table (65 values) into LDS ----
    if (t < NT * 13) {
        int n = t / 13;
        int k = t % 13;
        float bxy = bet_xy[b], bzv = bet_z[b], al = alpha[b];
        if (k < 8) {
            float d = (float)k;
            float g = expf(-d * d / (2.f * bxy * bxy)) * (INV / bxy);
            float p = g;
            for (int q = 0; q < n; ++q) p *= g;
            ct[n * 16 + k] = p;
        } else {
            float d = (float)(k - 8);
            float az = expf(-d * d / (2.f * bzv * bzv)) * (INV / bzv);
            float base = al * az;
            float p = base;
            for (int q = 0; q < n; ++q) p *= base;
            const float facs[NT] = {1.f, 2.f, 6.f, 24.f, 120.f};
            float sign = (n & 1) ? -1.f : 1.f;
            ct[n * 16 + k] = sign * p / (facs[n] * S);
        }
    }
    __syncthreads();

    // ---- hoist coefficients to wave-uniform scalars (SGPRs) ----
    float cg_[NT][8], cz_[NT][5];
#pragma unroll
    for (int n = 0; n < NT; ++n) {
#pragma unroll
        for (int k = 0; k < 8; ++k) cg_[n][k] = rfl(ct[n * 16 + k]);
#pragma unroll
        for (int k = 0; k < 5; ++k) cz_[n][k] = rfl(ct[n * 16 + 8 + k]);
    }
    __syncthreads();   // all ct/red reads done before xt staging overwrites alias

    // ---- staging descriptors (plane-invariant) ----
    const float* xb = x + (size_t)b * (D_ * HW_);
    int goff[NSEC], loff[NSEC];
#pragma unroll
    for (int k = 0; k < NSEC; ++k) {
        int i = t + k * NTHR;
        int r = i / XT_COLS, c = i - r * XT_COLS;
        int gh = h0 + r - 7, gw = w0 + c - 7;
        bool ok = (i < XT_CELLS) && gh >= 0 && gh < H_ && gw >= 0 && gw < W_;
        goff[k] = ok ? (gh * W_ + gw) : -1;
        loff[k] = (i < XT_CELLS) ? (r * XT_W + c) : (XT_SZ - 1);
    }
    // zero the 2 pad cols (62,63) of xt (read by quad-15 items)
    if (t < XT_H) {
        xtb[t * XT_W + 62] = 0.f;
        xtb[t * XT_W + 63] = 0.f;
    }
    // pre-stage first plane (zi = z0-4) into xt
    {
        int zi0 = z0 - 4;
        if (zi0 >= 0) {
#pragma unroll
            for (int k = 0; k < NSEC; ++k) {
                float v = 0.f;
                if (goff[k] >= 0) v = xb[(size_t)zi0 * HW_ + goff[k]];
                xtb[loff[k]] = v;
            }
        }
    }

    // ---- per-thread roles; rotate by 128 per adjacent block so co-resident
    //      blocks' heavy waves land on different SIMDs (128%16==0 keeps the
    //      lane<->group alignment DPP needs) ----
    const int bid = blockIdx.x + (int)gridDim.x * (blockIdx.y + (int)gridDim.y * blockIdx.z);
    const int rt  = (t + ((bid & 1) << 7)) & (NTHR - 1);

    // stage 1: 192 items = 12 rows x 16 quads; quad index = rt
    const bool s1act = (rt < 192);
    // stage 2: 192 items on rt in [64,256): l2 = rt-64; 12 rows x 16 groups
    const bool s2on = (rt >= 64);
    const int l2 = rt - 64;
    const int s2ro = l2 >> 4, s2cg = l2 & 15;
    const bool s2store = s2on && (s2cg < 12);

    float4 acc[9];
#pragma unroll
    for (int k = 0; k < 9; ++k) acc[k] = make_float4(0.f, 0.f, 0.f, 0.f);

#pragma unroll 1
    for (int p = 0; p <= NP; ++p) {
        __syncthreads();   // barrier1: xt holds plane zi; R'[(p-1)&1] complete

        const int zi = z0 - 4 + p;
        const bool do_s1 = (p < NP) && (zi >= 0) && (zi < D_) && s1act;
        const int  zn    = zi + 1;
        const bool pvalid = (p + 1 < NP) && (zn >= 0) && (zn < D_);

        // prefetch next plane into registers (long-latency window = whole iter)
        float pv[NSEC];
        if (pvalid) {
            const float* xp = xb + (size_t)zn * HW_;
#pragma unroll
            for (int k = 0; k < NSEC; ++k) pv[k] = (goff[k] >= 0) ? xp[goff[k]] : 0.f;
        }

        // ---- stage 1: h-conv plane zi: xt -> R'[p&1] (dense b128) ----
        if (do_s1) {
            const float4* x4 = (const float4*)(xtb + 4 * rt);
            float4* R4w = (float4*)(Rb + (p & 1) * RBUF);
            float4 ctr = x4[7 * 16];
            float4 sp[7];
#pragma unroll
            for (int k = 1; k <= 7; ++k)
                sp[k - 1] = f4add(x4[(7 - k) * 16], x4[(7 + k) * 16]);
#pragma unroll
            for (int n = 0; n < NT; ++n) {
                float c0 = cg_[n][0];
                float4 a;
                a.x = c0 * ctr.x; a.y = c0 * ctr.y;
                a.z = c0 * ctr.z; a.w = c0 * ctr.w;
#pragma unroll
                for (int k = 1; k <= 7; ++k) a = f4fma(cg_[n][k], sp[k - 1], a);
                R4w[rt + n * (R2_PL / 4)] = a;
            }
        }

        // ---- stage 2: w-conv + z-scatter, plane ziq = zi-1; own-quad read
        //      + DPP row_shl window assembly (no extra LDS traffic) ----
        if (p >= 1 && s2on) {
            const int ziq = zi - 1;
            if (ziq >= 0 && ziq < D_) {
                const float4* R4 = (const float4*)(Rb + ((p - 1) & 1) * RBUF) + l2;
                float4 u[5];
#pragma unroll
                for (int n = 0; n < NT; ++n) {
                    float4 A = R4[n * (R2_PL / 4)];
                    float win[18];
                    win[0]  = A.x; win[1]  = A.y; win[2]  = A.z; win[3]  = A.w;
                    win[4]  = dpp_shl<1>(A.x); win[5]  = dpp_shl<1>(A.y);
                    win[6]  = dpp_shl<1>(A.z); win[7]  = dpp_shl<1>(A.w);
                    win[8]  = dpp_shl<2>(A.x); win[9]  = dpp_shl<2>(A.y);
                    win[10] = dpp_shl<2>(A.z); win[11] = dpp_shl<2>(A.w);
                    win[12] = dpp_shl<3>(A.x); win[13] = dpp_shl<3>(A.y);
                    win[14] = dpp_shl<3>(A.z); win[15] = dpp_shl<3>(A.w);
                    win[16] = dpp_shl<4>(A.x); win[17] = dpp_shl<4>(A.y);
                    float c0 = cg_[n][0];
                    float4 qv;
                    qv.x = c0 * win[7];  qv.y = c0 * win[8];
                    qv.z = c0 * win[9];  qv.w = c0 * win[10];
#pragma unroll
                    for (int k = 1; k <= 7; ++k) {
                        float c = cg_[n][k];
                        qv.x = fmaf(c, win[7 - k]  + win[7 + k],  qv.x);
                        qv.y = fmaf(c, win[8 - k]  + win[8 + k],  qv.y);
                        qv.z = fmaf(c, win[9 - k]  + win[9 + k],  qv.z);
                        qv.w = fmaf(c, win[10 - k] + win[10 + k], qv.w);
                    }
                    if (n == 0) {
#pragma unroll
                        for (int j = 0; j < 5; ++j) {
                            float cz = cz_[0][j];
                            u[j].x = cz * qv.x; u[j].y = cz * qv.y;
                            u[j].z = cz * qv.z; u[j].w = cz * qv.w;
                        }
                    } else {
#pragma unroll
                        for (int j = 0; j < 5; ++j)
                            u[j] = f4fma(cz_[n][j], qv, u[j]);
                    }
                }
                acc[4] = f4add(acc[4], u[0]);
#pragma unroll
                for (int j = 1; j <= 4; ++j) {
                    acc[4 + j] = f4add(acc[4 + j], u[j]);
                    acc[4 - j] = f4add(acc[4 - j], u[j]);
                }
            }
            if (p - 1 >= 8 && s2store) {
                int z = z0 + (p - 1 - 8);
                size_t o = ((size_t)(b * D_ + z) * H_ + (h0 + s2ro)) * W_ + (w0 + 4 * s2cg);
                *(float4*)&out[o] = acc[0];
            }
#pragma unroll
            for (int k = 0; k < 8; ++k) acc[k] = acc[k + 1];
            acc[8] = make_float4(0.f, 0.f, 0.f, 0.f);
        }

        __syncthreads();   // barrier2: all xt reads (s1) complete

        // write prefetched plane zn into xt (single buffer)
        if (pvalid) {
#pragma unroll
            for (int k = 0; k < NSEC; ++k) xtb[loff[k]] = pv[k];
        }
    }
}

extern "C" void kernel_launch(void* const* d_in, const int* in_sizes, int n_in,
                              void* d_out, int out_size, void* d_ws, size_t ws_size,
                              hipStream_t stream) {
    const float* x      = (const float*)d_in[0];
    const float* bet_xy = (const float*)d_in[1];
    const float* bet_z  = (const float*)d_in[2];
    const float* alpha  = (const float*)d_in[3];
    float* out = (float*)d_out;

    hipLaunchKernelGGL(conv_kernel, dim3(W_ / TW, H_ / TH, B_ * (D_ / ZCHUNK)),
                       dim3(NTHR), 0, stream, x, bet_xy, bet_z, alpha, out);
}

// Round 7
// 134.085 us; speedup vs baseline: 1.3139x; 1.3139x over previous
//
#include <hip/hip_runtime.h>
#include <math.h>

#define B_ 4
#define D_ 32
#define H_ 192
#define W_ 192
#define HW_ (H_ * W_)

#define NT 5            // Taylor terms p = 1..5

#define TW 48           // 12 real col-groups (q=2..13); 16 staged quads
#define TH 12
#define NTHR 192        // 12 rows x 16 quads, one item per thread
#define ZCHUNK 16
#define NP (ZCHUNK + 8) // 24 iterations p = 0..23 (no stage lag)

#define XT_H 26         // TH + 14
#define XT_W 64         // 16 quads: staged cols = global [w0-8, w0+55]
#define XT_SZ (XT_H * XT_W)   // 1664 words
#define XT_Q (XT_H * 16)      // 416 staged quads

#define SMEM_WORDS (2 * XT_SZ)   // 3328 words = 13.3 KB

#define NTAPS (B_ * 9 * 15 * 15)
#define WS_FLOATS (B_ * 65)      // per-batch coefficient table in d_ws

__device__ inline float4 f4fma(float c, float4 a, float4 d) {
    d.x = fmaf(c, a.x, d.x); d.y = fmaf(c, a.y, d.y);
    d.z = fmaf(c, a.z, d.z); d.w = fmaf(c, a.w, d.w);
    return d;
}
__device__ inline float4 f4add(float4 a, float4 b) {
    a.x += b.x; a.y += b.y; a.z += b.z; a.w += b.w; return a;
}
__device__ inline float rfl(float x) {
    return __int_as_float(__builtin_amdgcn_readfirstlane(__float_as_int(x)));
}
// lane l <- lane l+N within each 16-lane DPP row; OOB -> 0. (HW-verified R5)
template<int N>
__device__ inline float dpp_shl(float v) {
    return __int_as_float(__builtin_amdgcn_update_dpp(
        0, __float_as_int(v), 0x100 | N, 0xF, 0xF, true));
}
// lane l <- lane l-N within each 16-lane DPP row; OOB -> 0.
template<int N>
__device__ inline float dpp_shr(float v) {
    return __int_as_float(__builtin_amdgcn_update_dpp(
        0, __float_as_int(v), 0x110 | N, 0xF, 0xF, true));
}

__device__ inline float tap_val(int idx, const float* bet_xy,
                                const float* bet_z, const float* alpha) {
    const float INV = 0.3989422804014327f;
    int bb = idx / 2025;
    int r  = idx % 2025;
    int dz = r / 225;
    int r2 = r % 225;
    int dh = r2 / 15;
    int dw = r2 % 15;
    float bxy = bet_xy[bb], bzv = bet_z[bb], al = alpha[bb];
    float zd = (float)(dz - 4), hd = (float)(dh - 7), wd = (float)(dw - 7);
    float az = expf(-zd * zd / (2.f * bzv * bzv)) * (INV / bzv);
    float gh = expf(-hd * hd / (2.f * bxy * bxy)) * (INV / bxy);
    float gw = expf(-wd * wd / (2.f * bxy * bxy)) * (INV / bxy);
    return 1.f - expf(-al * az * gh * gw);
}

__device__ inline float ct_val(int bb, int n, int k, float S,
                               const float* bet_xy, const float* bet_z,
                               const float* alpha) {
    const float INV = 0.3989422804014327f;
    float bxy = bet_xy[bb], bzv = bet_z[bb], al = alpha[bb];
    if (k < 8) {
        float d = (float)k;
        float g = expf(-d * d / (2.f * bxy * bxy)) * (INV / bxy);
        float p = g;
        for (int q = 0; q < n; ++q) p *= g;
        return p;
    } else {
        float d = (float)(k - 8);
        float az = expf(-d * d / (2.f * bzv * bzv)) * (INV / bzv);
        float base = al * az;
        float p = base;
        for (int q = 0; q < n; ++q) p *= base;
        const float facs[NT] = {1.f, 2.f, 6.f, 24.f, 120.f};
        float sign = (n & 1) ? -1.f : 1.f;
        return sign * p / (facs[n] * S);
    }
}

// One tiny block: exact tap-sum S + all 4 batches' 65-entry coefficient
// tables -> d_ws. Removes the exp-heavy prologue from all 512 main blocks.
__global__ __launch_bounds__(256)
void psf_precompute(const float* __restrict__ bet_xy,
                    const float* __restrict__ bet_z,
                    const float* __restrict__ alpha,
                    float* __restrict__ ws) {
    __shared__ float red[256];
    const int t = threadIdx.x;
    float local = 0.f;
#pragma unroll
    for (int s = 0; s < 32; ++s) {
        int idx = t + s * 256;
        if (idx < NTAPS) local += tap_val(idx, bet_xy, bet_z, alpha);
    }
    red[t] = local;
    __syncthreads();
    for (int s = 128; s > 0; s >>= 1) {
        if (t < s) red[t] += red[t + s];
        __syncthreads();
    }
    const float S = red[0];
    if (t < WS_FLOATS) {
        int bb = t / 65, j = t % 65;
        ws[t] = ct_val(bb, j / 13, j % 13, S, bet_xy, bet_z, alpha);
    }
}

// Fully fused separable-Taylor blur: one stage per iteration.
//   Each thread owns one (row, quad): h-conv from xt (15 dense b128 reads),
//   w-conv via DPP row_shr/shl on the in-register h result (no R' LDS),
//   z-scatter into a 9-deep output ring. xt double-buffered, 1 barrier/iter.
template<bool USE_WS>
__global__ __launch_bounds__(NTHR)
void conv_kernel(const float* __restrict__ x,
                 const float* __restrict__ bet_xy,
                 const float* __restrict__ bet_z,
                 const float* __restrict__ alpha,
                 const float* __restrict__ ct_ws,
                 float* __restrict__ out) {
    __shared__ __align__(16) float smem[SMEM_WORDS];
    float* xtb = smem;                 // [2][XT_SZ]
    float* red = smem;                 // alias: pre-loop only
    float* ct  = smem;                 // alias: pre-loop only, [65]

    const int t  = threadIdx.x;
    const int w0 = blockIdx.x * TW;
    const int h0 = blockIdx.y * TH;
    const int bz = blockIdx.z;
    const int b  = bz & 3;
    const int z0 = (bz >> 2) * ZCHUNK;
    const float4 z4 = make_float4(0.f, 0.f, 0.f, 0.f);

    // ---- coefficient table (65 values for batch b) into LDS ----
    if (USE_WS) {
        if (t < 65) ct[t] = ct_ws[b * 65 + t];
        __syncthreads();
    } else {
        float local = 0.f;
#pragma unroll
        for (int s = 0; s < 43; ++s) {
            int idx = t + s * NTHR;
            if (idx < NTAPS) local += tap_val(idx, bet_xy, bet_z, alpha);
        }
        red[t] = local;
        __syncthreads();
        for (int s = 128; s > 0; s >>= 1) {
            if (t < s && t + s < NTHR) red[t] += red[t + s];
            __syncthreads();
        }
        const float S = red[0];
        __syncthreads();
        if (t < 65) ct[t] = ct_val(b, t / 13, t % 13, S, bet_xy, bet_z, alpha);
        __syncthreads();
    }

    // ---- hoist coefficients to wave-uniform scalars (SGPRs) ----
    float cg_[NT][8], cz_[NT][5];
#pragma unroll
    for (int n = 0; n < NT; ++n) {
#pragma unroll
        for (int k = 0; k < 8; ++k) cg_[n][k] = rfl(ct[n * 13 + k]);
#pragma unroll
        for (int k = 0; k < 5; ++k) cz_[n][k] = rfl(ct[n * 13 + 8 + k]);
    }
    __syncthreads();   // ct reads done before xt staging overwrites alias

    // ---- staging descriptors: 416 quads, float4-aligned, zero-filled OOB ----
    const float* xb = x + (size_t)b * (D_ * HW_);
    int goff[3];
#pragma unroll
    for (int k = 0; k < 3; ++k) {
        int i = t + NTHR * k;
        if (i < XT_Q) {
            int row = i >> 4, qq = i & 15;
            int gh = h0 + row - 7, gc = w0 - 8 + 4 * qq;
            bool ok = (gh >= 0) && (gh < H_) && (gc >= 0) && (gc <= W_ - 4);
            goff[k] = ok ? (gh * W_ + gc) : -1;
        } else {
            goff[k] = -2;   // no item (k==2, t>=32)
        }
    }
    // pre-stage first plane (zi = z0-4) into xt buffer 0
    {
        int zi0 = z0 - 4;
        if (zi0 >= 0) {
            const float* xp = xb + (size_t)zi0 * HW_;
            float4* xn = (float4*)xtb;
            xn[t]        = (goff[0] >= 0) ? *(const float4*)(xp + goff[0]) : z4;
            xn[t + 192]  = (goff[1] >= 0) ? *(const float4*)(xp + goff[1]) : z4;
            if (goff[2] != -2)
                xn[t + 384] = (goff[2] >= 0) ? *(const float4*)(xp + goff[2]) : z4;
        }
    }

    // ---- per-thread item ----
    const int r1 = t >> 4;          // tile row 0..11
    const int q  = t & 15;          // quad 0..15 (== lane&15: DPP row-aligned)
    const bool qreal = (q >= 2) && (q <= 13);   // real output quads

    float4 acc[9];
#pragma unroll
    for (int k = 0; k < 9; ++k) acc[k] = z4;

#pragma unroll 1
    for (int p = 0; p < NP; ++p) {
        __syncthreads();   // xt[p&1] staged (iter p-1 writes complete)

        const int zi = z0 - 4 + p;
        const bool do_c = (zi >= 0) && (zi < D_);
        const int  zn = zi + 1;
        const bool pvalid = (p + 1 < NP) && (zn >= 0) && (zn < D_);

        // prefetch next plane into registers (hidden under this iter's compute)
        float4 pv0, pv1, pv2;
        if (pvalid) {
            const float* xp = xb + (size_t)zn * HW_;
            pv0 = (goff[0] >= 0) ? *(const float4*)(xp + goff[0]) : z4;
            pv1 = (goff[1] >= 0) ? *(const float4*)(xp + goff[1]) : z4;
            pv2 = z4;
            if (goff[2] >= 0) pv2 = *(const float4*)(xp + goff[2]);
        }

        // ---- fused h-conv + w-conv + z-scatter for plane zi ----
        if (do_c) {
            const float4* x4 = (const float4*)(xtb + (p & 1) * XT_SZ) + t;
            float4 ctr = x4[7 * 16];
            float4 sp[7];
#pragma unroll
            for (int k = 1; k <= 7; ++k)
                sp[k - 1] = f4add(x4[(7 - k) * 16], x4[(7 + k) * 16]);
            float4 u[5];
#pragma unroll
            for (int n = 0; n < NT; ++n) {
                // h-conv for own quad (cols 4q..4q+3 of the 64-col frame)
                float c0 = cg_[n][0];
                float4 hr;
                hr.x = c0 * ctr.x; hr.y = c0 * ctr.y;
                hr.z = c0 * ctr.z; hr.w = c0 * ctr.w;
#pragma unroll
                for (int k = 1; k <= 7; ++k) hr = f4fma(cg_[n][k], sp[k - 1], hr);
                // w window: win[i] = hr at frame col 4q-8+i (i=0..19)
                float win[20];
                win[8]  = hr.x; win[9]  = hr.y; win[10] = hr.z; win[11] = hr.w;
                win[0]  = dpp_shr<2>(hr.x); win[1]  = dpp_shr<2>(hr.y);
                win[2]  = dpp_shr<2>(hr.z); win[3]  = dpp_shr<2>(hr.w);
                win[4]  = dpp_shr<1>(hr.x); win[5]  = dpp_shr<1>(hr.y);
                win[6]  = dpp_shr<1>(hr.z); win[7]  = dpp_shr<1>(hr.w);
                win[12] = dpp_shl<1>(hr.x); win[13] = dpp_shl<1>(hr.y);
                win[14] = dpp_shl<1>(hr.z); win[15] = dpp_shl<1>(hr.w);
                win[16] = dpp_shl<2>(hr.x); win[17] = dpp_shl<2>(hr.y);
                win[18] = dpp_shl<2>(hr.z); win[19] = dpp_shl<2>(hr.w);
                float4 qv;
                qv.x = c0 * win[8];  qv.y = c0 * win[9];
                qv.z = c0 * win[10]; qv.w = c0 * win[11];
#pragma unroll
                for (int k = 1; k <= 7; ++k) {
                    float c = cg_[n][k];
                    qv.x = fmaf(c, win[8 - k]  + win[8 + k],  qv.x);
                    qv.y = fmaf(c, win[9 - k]  + win[9 + k],  qv.y);
                    qv.z = fmaf(c, win[10 - k] + win[10 + k], qv.z);
                    qv.w = fmaf(c, win[11 - k] + win[11 + k], qv.w);
                }
                if (n == 0) {
#pragma unroll
                    for (int j = 0; j < 5; ++j) {
                        float cz = cz_[0][j];
                        u[j].x = cz * qv.x; u[j].y = cz * qv.y;
                        u[j].z = cz * qv.z; u[j].w = cz * qv.w;
                    }
                } else {
#pragma unroll
                    for (int j = 0; j < 5; ++j)
                        u[j] = f4fma(cz_[n][j], qv, u[j]);
                }
            }
            acc[4] = f4add(acc[4], u[0]);
#pragma unroll
            for (int j = 1; j <= 4; ++j) {
                acc[4 + j] = f4add(acc[4 + j], u[j]);
                acc[4 - j] = f4add(acc[4 - j], u[j]);
            }
        }

        // ---- store completed plane z = zi-4 = z0 + p - 8 ----
        if (p >= 8 && qreal) {
            int z = z0 + (p - 8);
            size_t o = ((size_t)(b * D_ + z) * H_ + (h0 + r1)) * W_ + (w0 - 8 + 4 * q);
            *(float4*)&out[o] = acc[0];
        }
#pragma unroll
        for (int k = 0; k < 8; ++k) acc[k] = acc[k + 1];
        acc[8] = z4;

        // write prefetched plane zn into xt[(p+1)&1]
        if (pvalid) {
            float4* xn = (float4*)(xtb + ((p + 1) & 1) * XT_SZ);
            xn[t]       = pv0;
            xn[t + 192] = pv1;
            if (goff[2] != -2) xn[t + 384] = pv2;
        }
    }
}

extern "C" void kernel_launch(void* const* d_in, const int* in_sizes, int n_in,
                              void* d_out, int out_size, void* d_ws, size_t ws_size,
                              hipStream_t stream) {
    const float* x      = (const float*)d_in[0];
    const float* bet_xy = (const float*)d_in[1];
    const float* bet_z  = (const float*)d_in[2];
    const float* alpha  = (const float*)d_in[3];
    float* out = (float*)d_out;

    dim3 grid(W_ / TW, H_ / TH, B_ * (D_ / ZCHUNK));
    if (d_ws != nullptr && ws_size >= WS_FLOATS * sizeof(float)) {
        hipLaunchKernelGGL(psf_precompute, dim3(1), dim3(256), 0, stream,
                           bet_xy, bet_z, alpha, (float*)d_ws);
        hipLaunchKernelGGL(HIP_KERNEL_NAME(conv_kernel<true>), grid, dim3(NTHR),
                           0, stream, x, bet_xy, bet_z, alpha,
                           (const float*)d_ws, out);
    } else {
        hipLaunchKernelGGL(HIP_KERNEL_NAME(conv_kernel<false>), grid, dim3(NTHR),
                           0, stream, x, bet_xy, bet_z, alpha,
                           (const float*)nullptr, out);
    }
}